// Round 13
// baseline (125.879 us; speedup 1.0000x reference)
//
#include <hip/hip_runtime.h>

#define NSENT 64
#define NCAND 8192
#define LMAX  512
#define KOUT  128
#define TPB   512
#define CHUNK 1024
#define NCHUNK (NCAND / CHUNK)   // 8
#define P1    1024               // serial-greedy prefix
#define NCH2  ((NCAND - P1) / TPB)  // 14 pass-2 chunks
#define SURV_CAP 2048

#if defined(__has_builtin)
#if __has_builtin(__builtin_amdgcn_readlane)
#define READLANE(v, l) __builtin_amdgcn_readlane((unsigned)(v), (unsigned)(l))
#endif
#endif
#ifndef READLANE
#define READLANE(v, l) ((unsigned)__shfl((int)(v), (int)(l)))
#endif

// ---------------------------------------------------------------------------
// Kernel A (unchanged R7 form): 512 blocks (sentence = bid>>3, chunk = bid&7).
// Bitonic-sort 1024 u64 keys in LDS, write sorted chunk to ws.
// Key: high 32 = descending-orderable score bits, low 31 = (idx<<18)|(st<<9)|en
// ---------------------------------------------------------------------------
__global__ __launch_bounds__(TPB) void sort_chunks_kernel(
    const float* __restrict__ scores,
    const int*   __restrict__ starts,
    const int*   __restrict__ ends,
    unsigned long long* __restrict__ ws)
{
    __shared__ unsigned long long lk[CHUNK];
    const int  bid   = blockIdx.x;
    const int  sent  = bid >> 3;
    const int  chunk = bid & 7;
    const int  tid   = threadIdx.x;
    const long gbase = (long)sent * NCAND + (long)chunk * CHUNK;

    for (int i = tid; i < CHUNK; i += TPB) {
        unsigned u  = __float_as_uint(scores[gbase + i]);
        unsigned o  = (u & 0x80000000u) ? ~u : (u | 0x80000000u); // asc-orderable
        unsigned d  = ~o;                                          // descending
        unsigned st = (unsigned)starts[gbase + i];
        unsigned en = (unsigned)ends[gbase + i];
        unsigned gi = (unsigned)(chunk * CHUNK + i);               // idx in sentence
        lk[i] = ((unsigned long long)d << 32) | (gi << 18) | (st << 9) | en;
    }

    for (int k = 2; k <= CHUNK; k <<= 1) {
        for (int j = k >> 1; j > 0; j >>= 1) {
            __syncthreads();
            const int p   = tid;               // CHUNK/2 == TPB: one CX per thread
            const int low = p & (j - 1);
            const int i   = ((p - low) << 1) | low;
            const int q   = i | j;
            unsigned long long a = lk[i];
            unsigned long long b = lk[q];
            bool up = ((i & k) == 0);
            if ((a > b) == up) { lk[i] = b; lk[q] = a; }
        }
    }
    __syncthreads();

    unsigned long long* wo = ws + (long)bid * CHUNK;
    for (int i = tid; i < CHUNK; i += TPB) wo[i] = lk[i];
}

// crossing test vs sparse range-max/min tables:
// crossing iff max s2e[st+1..en] > en  or  min e2s[st..en-1] < st
__device__ __forceinline__ bool tt_cross(int st, int en,
    const int (*T1)[LMAX], const int (*T2)[LMAX])
{
    const int wd = en - st;
    if (wd <= 0) return false;
    if (wd < 32) {
        const int k   = 31 - __clz(wd);
        const int off = 1 << k;
        const int mx  = max(T1[k][st + 1], T1[k][en + 1 - off]);
        const int mn  = min(T2[k][st],     T2[k][en - off]);
        return (mx > en) || (mn < st);
    }
    bool cross = false;
    for (int j = st; j <= en; ++j)
        cross |= ((j > st) && (T1[0][j] > en)) || ((j < en) && (T2[0][j] < st));
    return cross;
}

// Serial pop loop, NO LDS ops in the dependency chain (acc_list store is
// fire-and-forget). 2-deep: accept1, register-kill, accept2 from the updated
// ballot (earlier lanes are provably dead). Exact sequential semantics.
// mutates: alive, n. uses: pay, st, en, lane, acc_list.
#define POP_WINDOW_LOOP()                                                      \
    for (;;) {                                                                 \
        if (n >= KOUT) break;                                                  \
        unsigned long long anyb = __ballot((int)alive);                        \
        if (anyb == 0ull) break;                                               \
        const int l1 = __ffsll((long long)anyb) - 1;                           \
        const unsigned sp1 = READLANE(pay, l1);                                \
        const int se1 = (int)(sp1 & 511u), ss1 = (int)((sp1 >> 9) & 511u);     \
        if (lane == l1) { acc_list[n] = sp1; alive = false; }                  \
        const bool c1 = ((st < ss1) & (ss1 <= en) & (se1 > en)) |              \
                        ((ss1 < st) & (se1 >= st) & (se1 < en));               \
        alive = alive & !c1;                                                   \
        if (n + 1 >= KOUT) { ++n; break; }                                     \
        anyb = __ballot((int)alive);                                           \
        if (anyb == 0ull) { ++n; break; }                                      \
        const int l2 = __ffsll((long long)anyb) - 1;                           \
        const unsigned sp2 = READLANE(pay, l2);                                \
        const int se2 = (int)(sp2 & 511u), ss2 = (int)((sp2 >> 9) & 511u);     \
        if (lane == l2) { acc_list[n + 1] = sp2; alive = false; }              \
        const bool c2 = ((st < ss2) & (ss2 <= en) & (se2 > en)) |              \
                        ((ss2 < st) & (se2 >= st) & (se2 < en));               \
        alive = alive & !c2;                                                   \
        n += 2;                                                                \
    }

// Window-end TT update replay: broadcast-read each accept, 62-lane atomic
// burst per accept (independent, pipelined, off the pop chain).
#define TT_BATCH(n0_)                                                          \
    if (n < KOUT) {                                                            \
        _Pragma("unroll 2")                                                    \
        for (int a = (n0_); a < n; ++a) {                                      \
            const unsigned ap = acc_list[a];                                   \
            const int aen = (int)(ap & 511u);                                  \
            const int ast = (int)((ap >> 9) & 511u);                           \
            if (lane < 31)      { const int ii = ast - j_m; if (ii >= 0) atomicMax(&rowU[ii], aen); } \
            else if (lane < 62) { const int ii = aen - j_m; if (ii >= 0) atomicMin(&rowU[ii], ast); } \
        }                                                                      \
    }

// ---------------------------------------------------------------------------
// Kernel B: 64 blocks x 512 threads.
//  1. load 8 sorted runs -> LDS, merge-path merge (3 stages, 512 threads)
//  2. greedy, 3 phases:
//     P1: wave 0, windows over first P1=1024 candidates
//     P2: ALL threads stale-filter remaining 7168 vs TT snapshot (kills are
//         monotone => final), stable-compact survivors (~170) into surv[]
//     P3: wave 0, windows over surv[]; overflow tail (normally never)
//  3. parallel rank-sort of the <=128 selected by (start,end)
// ---------------------------------------------------------------------------
__global__ __launch_bounds__(TPB) void merge_greedy_kernel(
    const unsigned long long* __restrict__ ws,
    int* __restrict__ out)
{
    __shared__ __align__(16) unsigned long long keys[NCAND];  // 64 KiB
    __shared__ int TT1[5][LMAX];              // 10 KiB
    __shared__ int TT2[5][LMAX];              // 10 KiB
    __shared__ unsigned surv[SURV_CAP];       // 8 KiB (payloads, sorted order)
    __shared__ unsigned long long pmask[NCH2][8];
    __shared__ unsigned acc_list[KOUT];
    __shared__ int n_sh, nsurv_sh, tail_sh;
    __shared__ unsigned mkbuf[KOUT];
    __shared__ unsigned paybuf[KOUT];

    const int sent = blockIdx.x;
    const int tid  = threadIdx.x;
    const unsigned long long* wi = ws + (long)sent * NCAND;

    for (int i = tid; i < 5 * LMAX; i += TPB) {
        (&TT1[0][0])[i] = -1;
        (&TT2[0][0])[i] = LMAX;
    }
    if (tid == 0) { n_sh = 0; nsurv_sh = 0; tail_sh = NCAND; }
    {
        const ulonglong2* wi2 = (const ulonglong2*)wi;
        ulonglong2* k2 = (ulonglong2*)keys;
        for (int i = tid; i < NCAND / 2; i += TPB) k2[i] = wi2[i];
    }
    __syncthreads();

    // ---- merge: 8 sorted runs of 1024 -> 1 run of 8192 (3 stages) ----------
    #pragma unroll
    for (int stg = 0; stg < 3; ++stg) {
        const int Lh  = CHUNK << stg;          // 1024, 2048, 4096
        const int tpp = Lh >> 3;               // threads per pair
        const int pair = tid / tpp;
        const int o    = (tid % tpp) * 16;
        const unsigned long long* A = keys + pair * (Lh * 2);
        const unsigned long long* B = A + Lh;
        int lo = (o > Lh) ? o - Lh : 0;
        int hi = (o < Lh) ? o : Lh;
        while (lo < hi) {                      // smallest i : A[i] > B[o-1-i]
            int mid = (lo + hi) >> 1;
            if (A[mid] <= B[o - 1 - mid]) lo = mid + 1; else hi = mid;
        }
        int i = lo, j = o - lo;
        unsigned long long r[16];
        #pragma unroll
        for (int x = 0; x < 16; ++x) {
            bool ta = (j >= Lh) || (i < Lh && A[i] <= B[j]);
            r[x] = ta ? A[i++] : B[j++];
        }
        __syncthreads();                       // all reads done before overwrite
        unsigned long long* O = keys + pair * (Lh * 2) + o;
        #pragma unroll
        for (int x = 0; x < 16; ++x) O[x] = r[x];
        __syncthreads();
    }

    const unsigned* kw = (const unsigned*)keys;     // low word = payload

    // ---- P1: wave 0, serial windows over keys[0..P1) ------------------------
    if (tid < 64) {
        const int lane = tid;
        const int sidel = (lane < 31) ? lane : (lane - 31);
        const int k_m   = 31 - __clz(sidel + 1);
        const int j_m   = sidel + 1 - (1 << k_m);
        int* const rowU = (lane < 31) ? &TT1[k_m][0] : &TT2[k_m][0];

        int n = 0;
        for (int w = 0; w < P1 / 64 && n < KOUT; ++w) {
            const unsigned pay = kw[(w * 64 + lane) << 1];
            const int en = (int)(pay & 511u);
            const int st = (int)((pay >> 9) & 511u);
            bool alive = !tt_cross(st, en, TT1, TT2);
            const int n0w = n;
            POP_WINDOW_LOOP();
            TT_BATCH(n0w);
        }
        if (lane == 0) n_sh = n;
    }
    __syncthreads();                            // TT + n_sh visible

    // ---- P2: all threads, stale filter + stable compaction ------------------
    const int n1 = n_sh;
    unsigned mypay[NCH2];
    bool     myalive[NCH2];
    if (n1 < KOUT) {
        #pragma unroll
        for (int c = 0; c < NCH2; ++c) {
            const int i = P1 + c * TPB + tid;
            const unsigned pay = kw[i << 1];
            const int en = (int)(pay & 511u);
            const int st = (int)((pay >> 9) & 511u);
            const bool alive = !tt_cross(st, en, TT1, TT2);
            mypay[c] = pay; myalive[c] = alive;
            const unsigned long long b = __ballot((int)alive);
            if ((tid & 63) == 0) pmask[c][tid >> 6] = b;
        }
    }
    __syncthreads();
    if (n1 < KOUT) {
        const int myw = tid >> 6;
        const unsigned long long below = (1ull << (tid & 63)) - 1ull;
        unsigned run = 0;
        #pragma unroll
        for (int c = 0; c < NCH2; ++c) {
            unsigned off = 0;
            #pragma unroll
            for (int w = 0; w < 8; ++w) {
                const unsigned long long m = pmask[c][w];
                if (w == myw) off = run + (unsigned)__popcll(m & below);
                run += (unsigned)__popcll(m);
            }
            if (myalive[c]) {
                if (off < SURV_CAP) surv[off] = mypay[c];
                else atomicMin(&tail_sh, P1 + c * TPB + tid);  // first unstored
            }
        }
        if (tid == 0) nsurv_sh = (run < SURV_CAP) ? (int)run : SURV_CAP;
    }
    __syncthreads();

    // ---- P3: wave 0, windows over surv[], then (rare) tail ------------------
    if (tid < 64) {
        const int lane = tid;
        const int sidel = (lane < 31) ? lane : (lane - 31);
        const int k_m   = 31 - __clz(sidel + 1);
        const int j_m   = sidel + 1 - (1 << k_m);
        int* const rowU = (lane < 31) ? &TT1[k_m][0] : &TT2[k_m][0];

        int n = n_sh;
        const int nsurv = nsurv_sh;
        for (int s = 0; s < nsurv && n < KOUT; s += 64) {
            const int i = s + lane;
            const bool have = i < nsurv;
            const unsigned pay = surv[have ? i : 0];
            const int en = (int)(pay & 511u);
            const int st = (int)((pay >> 9) & 511u);
            bool alive = have && !tt_cross(st, en, TT1, TT2);
            const int n0w = n;
            POP_WINDOW_LOOP();
            TT_BATCH(n0w);
        }
        // overflow tail: re-scan candidates from tail_sh (monotone kills make
        // re-filtering the dead ones harmless). Normally tail_sh == NCAND.
        for (int cb = tail_sh; cb < NCAND && n < KOUT; cb += 64) {
            const int i = cb + lane;
            const bool have = i < NCAND;
            const unsigned pay = kw[(have ? i : 0) << 1];
            const int en = (int)(pay & 511u);
            const int st = (int)((pay >> 9) & 511u);
            bool alive = have && !tt_cross(st, en, TT1, TT2);
            const int n0w = n;
            POP_WINDOW_LOOP();
            TT_BATCH(n0w);
        }
        if (lane == 0) n_sh = n;
    }
    __syncthreads();                            // publish acc_list / n_sh

    // ---- final (start,end) rank-sort + output (first 128 threads) ----------
    const int n = n_sh;
    if (tid < KOUT) {
        const unsigned p = (tid < n) ? acc_list[tid] : acc_list[0];
        paybuf[tid] = p;
        mkbuf[tid]  = ((p & 0x3FFFFu) << 7) | (unsigned)tid;   // stable tie-break
    }
    __syncthreads();
    if (tid < KOUT) {
        const unsigned mk = mkbuf[tid];
        int r = 0;
        #pragma unroll 8
        for (int t2 = 0; t2 < KOUT; ++t2) r += (mkbuf[t2] < mk) ? 1 : 0;
        out[sent * KOUT + r] = (int)(paybuf[tid] >> 18);
    }
}

// ---------------------------------------------------------------------------
// Fallback monolithic kernel (round-2, known-correct) if ws is too small.
// ---------------------------------------------------------------------------
__global__ __launch_bounds__(TPB) void extract_spans_mono(
    const float* __restrict__ scores,
    const int*   __restrict__ starts,
    const int*   __restrict__ ends,
    int*         __restrict__ out)
{
    __shared__ unsigned long long keys[NCAND];
    __shared__ unsigned acc_list[KOUT];
    __shared__ unsigned long long amask[TPB/64];
    __shared__ unsigned mkbuf[KOUT];
    __shared__ unsigned paybuf[KOUT];

    const int  sent = blockIdx.x;
    const int  tid  = threadIdx.x;
    const long base = (long)sent * NCAND;

    for (int i = tid; i < NCAND; i += TPB) {
        unsigned u = __float_as_uint(scores[base + i]);
        unsigned o = (u & 0x80000000u) ? ~u : (u | 0x80000000u);
        unsigned d = ~o;
        unsigned st = (unsigned)starts[base + i];
        unsigned en = (unsigned)ends[base + i];
        keys[i] = ((unsigned long long)d << 32) | ((unsigned)i << 18) | (st << 9) | en;
    }
    for (int k = 2; k <= NCAND; k <<= 1) {
        for (int j = k >> 1; j > 0; j >>= 1) {
            __syncthreads();
            for (int p = tid; p < NCAND / 2; p += TPB) {
                int low = p & (j - 1);
                int i   = ((p - low) << 1) | low;
                int q   = i | j;
                unsigned long long a = keys[i];
                unsigned long long b = keys[q];
                bool up = ((i & k) == 0);
                if ((a > b) == up) { keys[i] = b; keys[q] = a; }
            }
        }
    }
    __syncthreads();

    int  nn   = 0;
    bool done = false;
    for (int cb = 0; cb < NCAND && !done; cb += TPB) {
        const unsigned pay = (unsigned)keys[cb + tid];
        const int en = (int)(pay & 511u);
        const int st = (int)((pay >> 9) & 511u);
        bool alive = true;
        for (int a = 0; a < nn; ++a) {
            unsigned ap = acc_list[a];
            int ae = (int)(ap & 511u), as = (int)((ap >> 9) & 511u);
            if ((st < as && as <= en && ae > en) || (as < st && ae >= st && ae < en)) {
                alive = false; break;
            }
        }
        for (;;) {
            unsigned long long m = __ballot((int)alive);
            if ((tid & 63) == 0) amask[tid >> 6] = m;
            __syncthreads();
            int s = -1;
            #pragma unroll
            for (int w = 0; w < TPB / 64; ++w) {
                unsigned long long mw = amask[w];
                if (s < 0 && mw) s = (w << 6) + __ffsll((long long)mw) - 1;
            }
            __syncthreads();
            if (s < 0) break;
            unsigned spay = (unsigned)keys[cb + s];
            int sen = (int)(spay & 511u), sst = (int)((spay >> 9) & 511u);
            if (tid == 0) acc_list[nn] = spay;
            ++nn;
            if (nn == KOUT) { done = true; break; }
            if (alive) {
                alive = (tid != s) &&
                        !((st < sst && sst <= en && sen > en) ||
                          (sst < st && sen >= st && sen < en));
            }
        }
    }
    __syncthreads();
    if (tid < KOUT) {
        unsigned pay = (tid < nn) ? acc_list[tid] : acc_list[0];
        paybuf[tid] = pay;
        mkbuf[tid]  = ((pay & 0x3FFFFu) << 7) | (unsigned)tid;
    }
    __syncthreads();
    if (tid < KOUT) {
        unsigned mk = mkbuf[tid];
        int rank = 0;
        for (int t2 = 0; t2 < KOUT; ++t2)
            rank += (mkbuf[t2] < mk) ? 1 : 0;
        out[sent * KOUT + rank] = (int)(paybuf[tid] >> 18);
    }
}

extern "C" void kernel_launch(void* const* d_in, const int* in_sizes, int n_in,
                              void* d_out, int out_size, void* d_ws, size_t ws_size,
                              hipStream_t stream) {
    const float* scores = (const float*)d_in[0];
    const int*   starts = (const int*)d_in[1];
    const int*   ends   = (const int*)d_in[2];
    int*         out    = (int*)d_out;

    const size_t ws_needed = (size_t)NSENT * NCAND * sizeof(unsigned long long); // 4 MiB
    if (ws_size >= ws_needed) {
        unsigned long long* ws = (unsigned long long*)d_ws;
        sort_chunks_kernel<<<NSENT * NCHUNK, TPB, 0, stream>>>(scores, starts, ends, ws);
        merge_greedy_kernel<<<NSENT, TPB, 0, stream>>>(ws, out);
    } else {
        extract_spans_mono<<<NSENT, TPB, 0, stream>>>(scores, starts, ends, out);
    }
}